// Round 10
// baseline (926.666 us; speedup 1.0000x reference)
//
#include <hip/hip_runtime.h>
#include <cstddef>

#define BATCH 128

typedef _Float16 f16;
typedef _Float16 half8 __attribute__((ext_vector_type(8)));
typedef float floatx16 __attribute__((ext_vector_type(16)));

// ---------------------------------------------------------------------------
// fc_init: out[m, n] = bias[n]
// ---------------------------------------------------------------------------
__global__ __launch_bounds__(256) void fc_init(
    float* __restrict__ out, const float* __restrict__ bias, int M, int N, int stride)
{
    int idx = blockIdx.x * 256 + threadIdx.x;
    if (idx >= M * N) return;
    int n = idx % N, m = idx / N;
    out[(size_t)m * stride + n] = bias[n];
}

// ---------------------------------------------------------------------------
// fc_mfma: split-K FC partial via v_mfma_f32_32x32x16_f16.
// ---------------------------------------------------------------------------
__global__ __launch_bounds__(256) void fc_mfma(
    const float* __restrict__ A, const float* __restrict__ W,
    float* __restrict__ out, int N, int K, int KC, int out_stride, int relu_in)
{
    __shared__ f16 As[128 * 34];
    __shared__ f16 Ws[64 * 34];
    int tid = threadIdx.x;
    int lane = tid & 63, wv = tid >> 6;
    int m32 = lane & 31, h = lane >> 5;
    int n0 = blockIdx.x * 64;
    int k0 = blockIdx.y * KC;

    floatx16 acc[2];
    #pragma unroll
    for (int nt = 0; nt < 2; nt++)
        #pragma unroll
        for (int r = 0; r < 16; r++) acc[nt][r] = 0.f;

    for (int ks = 0; ks < KC; ks += 32) {
        #pragma unroll
        for (int q4 = 0; q4 < 4; q4++) {
            int e = tid + q4 * 256;
            int m = e >> 3, q = e & 7;
            float4 v = *(const float4*)(A + (size_t)m * K + k0 + ks + q * 4);
            if (relu_in) {
                v.x = fmaxf(v.x, 0.f); v.y = fmaxf(v.y, 0.f);
                v.z = fmaxf(v.z, 0.f); v.w = fmaxf(v.w, 0.f);
            }
            f16* dst = As + m * 34 + q * 4;
            dst[0] = (f16)v.x; dst[1] = (f16)v.y; dst[2] = (f16)v.z; dst[3] = (f16)v.w;
        }
        #pragma unroll
        for (int q4 = 0; q4 < 2; q4++) {
            int e = tid + q4 * 256;
            int nn = e >> 3, q = e & 7;
            int n = n0 + nn;
            float4 v = (n < N) ? *(const float4*)(W + (size_t)n * K + k0 + ks + q * 4)
                               : make_float4(0.f, 0.f, 0.f, 0.f);
            f16* dst = Ws + nn * 34 + q * 4;
            dst[0] = (f16)v.x; dst[1] = (f16)v.y; dst[2] = (f16)v.z; dst[3] = (f16)v.w;
        }
        __syncthreads();
        #pragma unroll
        for (int kh = 0; kh < 2; kh++) {
            half8 af = *(const half8*)(As + (wv * 32 + m32) * 34 + kh * 16 + h * 8);
            #pragma unroll
            for (int nt = 0; nt < 2; nt++) {
                half8 bf = *(const half8*)(Ws + (nt * 32 + m32) * 34 + kh * 16 + h * 8);
                acc[nt] = __builtin_amdgcn_mfma_f32_32x32x16_f16(af, bf, acc[nt], 0, 0, 0);
            }
        }
        __syncthreads();
    }
    #pragma unroll
    for (int nt = 0; nt < 2; nt++) {
        #pragma unroll
        for (int r = 0; r < 16; r++) {
            int m = wv * 32 + (r & 3) + 8 * (r >> 2) + 4 * h;
            int n = n0 + nt * 32 + m32;
            if (n < N) atomicAdd(&out[(size_t)m * out_stride + n], acc[nt][r]);
        }
    }
}

// ---------------------------------------------------------------------------
// Direct conv 3x3 (+relu), fp32 — used only for ih1 (C=1).
// ---------------------------------------------------------------------------
__global__ void conv_direct_kernel(
    const float* __restrict__ in, long inBatchStride,
    const float* __restrict__ w, const float* __restrict__ bias,
    float* __restrict__ out,
    int C, int H, int Wd, int K, int OH, int OW, int stride, int pad, int total)
{
    int idx = blockIdx.x * 256 + threadIdx.x;
    if (idx >= total) return;
    int ox = idx % OW;
    int oy = (idx / OW) % OH;
    int k  = (idx / (OW * OH)) % K;
    int b  = idx / (OW * OH * K);
    const float* inb = in + (size_t)b * inBatchStride;
    float s = bias[k];
    for (int c = 0; c < C; c++) {
        const float* ip = inb + (size_t)c * H * Wd;
        const float* wp = w + ((size_t)k * C + c) * 9;
        #pragma unroll
        for (int r = 0; r < 3; r++) {
            int iy = oy * stride - pad + r;
            if (iy < 0 || iy >= H) continue;
            #pragma unroll
            for (int s2 = 0; s2 < 3; s2++) {
                int ix = ox * stride - pad + s2;
                if (ix < 0 || ix >= Wd) continue;
                s += ip[iy * Wd + ix] * wp[r * 3 + s2];
            }
        }
    }
    out[idx] = s > 0.f ? s : 0.f;
}

// ---------------------------------------------------------------------------
// ih_w2 transpose: (128,64,9) -> wT2[(c*9+rs)*128 + k]
// ---------------------------------------------------------------------------
__global__ void transpose_w2_kernel(const float* __restrict__ w, float* __restrict__ wT)
{
    int idx = blockIdx.x * 256 + threadIdx.x;
    if (idx >= 73728) return;
    int k = idx / 576;
    int rem = idx % 576;
    wT[rem * 128 + k] = w[idx];
}

// ---------------------------------------------------------------------------
// ih2: conv 64->128, 12x12 -> 6x6, s2 p1, relu.
// ---------------------------------------------------------------------------
__global__ __launch_bounds__(256) void ih2_kernel(
    const float* __restrict__ ih1, const float* __restrict__ wT2,
    const float* __restrict__ bias, float* __restrict__ out)
{
    __shared__ float in_s[4 * 144];
    __shared__ float w_s[4 * 1152];
    int b = blockIdx.x;
    int tid = threadIdx.x;
    int k = tid & 127, half = tid >> 7;
    int oy0 = half * 3;
    float acc[3][6];
    #pragma unroll
    for (int r = 0; r < 3; r++)
        #pragma unroll
        for (int c = 0; c < 6; c++) acc[r][c] = 0.f;

    for (int c0 = 0; c0 < 64; c0 += 4) {
        for (int e = tid; e < 576; e += 256)
            in_s[e] = ih1[((size_t)b * 64 + c0) * 144 + e];
        for (int e = tid; e < 4608; e += 256)
            w_s[e] = wT2[c0 * 1152 + e];
        __syncthreads();
        #pragma unroll
        for (int cc = 0; cc < 4; cc++) {
            float wr[9];
            #pragma unroll
            for (int rs = 0; rs < 9; rs++) wr[rs] = w_s[cc * 1152 + rs * 128 + k];
            #pragma unroll
            for (int row = 0; row < 3; row++) {
                int oy = oy0 + row;
                #pragma unroll
                for (int r = 0; r < 3; r++) {
                    int iy = 2 * oy - 1 + r;
                    float v[13];
                    if (iy >= 0) {
                        float4 a = *(const float4*)&in_s[cc * 144 + iy * 12];
                        float4 bq = *(const float4*)&in_s[cc * 144 + iy * 12 + 4];
                        float4 cq = *(const float4*)&in_s[cc * 144 + iy * 12 + 8];
                        v[0] = 0.f;
                        v[1] = a.x;  v[2] = a.y;  v[3] = a.z;  v[4] = a.w;
                        v[5] = bq.x; v[6] = bq.y; v[7] = bq.z; v[8] = bq.w;
                        v[9] = cq.x; v[10] = cq.y; v[11] = cq.z; v[12] = cq.w;
                    } else {
                        #pragma unroll
                        for (int u = 0; u < 13; u++) v[u] = 0.f;
                    }
                    #pragma unroll
                    for (int s = 0; s < 3; s++) {
                        float wv = wr[r * 3 + s];
                        #pragma unroll
                        for (int ox = 0; ox < 6; ox++)
                            acc[row][ox] += v[2 * ox + s] * wv;
                    }
                }
            }
        }
        __syncthreads();
    }
    float bv = bias[k];
    #pragma unroll
    for (int row = 0; row < 3; row++)
        #pragma unroll
        for (int ox = 0; ox < 6; ox++) {
            float vv = acc[row][ox] + bv;
            out[((size_t)(b * 128 + k) * 6 + oy0 + row) * 6 + ox] = vv > 0.f ? vv : 0.f;
        }
}

// ---------------------------------------------------------------------------
// enc1: conv 1->256, 24x24 -> 22x22, relu. f16 channel-last, swizzled.
// ---------------------------------------------------------------------------
__global__ void enc1_kernel(const float* __restrict__ patch,
                            const float* __restrict__ w,
                            const float* __restrict__ bias,
                            f16* __restrict__ h1, int total)
{
    int idx = blockIdx.x * 256 + threadIdx.x;
    if (idx >= total) return;
    int k  = idx & 255;
    int pg = (idx >> 8) % 484;
    int b  = idx / (484 * 256);
    int y = pg / 22, x = pg % 22;
    const float* pb = patch + (size_t)b * 1152 + y * 24 + x;
    const float* wk = w + k * 9;
    float s = bias[k];
    #pragma unroll
    for (int r = 0; r < 3; r++)
        #pragma unroll
        for (int c = 0; c < 3; c++)
            s += pb[r * 24 + c] * wk[r * 3 + c];
    s = s > 0.f ? s : 0.f;
    int cpos = (k & ~31) + (((((k >> 3) & 3) ^ ((pg >> 1) & 3))) << 3) + (k & 7);
    h1[((size_t)b * 484 + pg) * 256 + cpos] = (f16)s;
}

// ---------------------------------------------------------------------------
// Weight transform to MFMA-A fragment-major f16.
// ---------------------------------------------------------------------------
__global__ void wtrans_kernel(const float* __restrict__ w, f16* __restrict__ wf,
                              int C, int NKG, int total)
{
    int idx = blockIdx.x * 256 + threadIdx.x;
    if (idx >= total) return;
    int j    = idx & 7;
    int lane = (idx >> 3) & 63;
    int kh   = (idx >> 9) & 1;
    int kg   = (idx >> 10) % NKG;
    int rest = idx / (NKG << 10);
    int rs   = rest % 9;
    int c0   = rest / 9;
    int k = kg * 32 + (lane & 31);
    int c = c0 * 32 + kh * 16 + ((lane >> 5) << 3) + j;
    wf[idx] = (f16)w[((size_t)k * C + c) * 9 + rs];
}

// ---------------------------------------------------------------------------
// conv_mfma4: 3x3 conv s1 p0 +relu, v_mfma_f32_32x32x16_f16.
// acc[2][2] = 64 AGPR + 64 arch VGPR = 128 regs/wave -> 4 waves/SIMD
// (R9: 3 waves gave MfmaUtil 36%; the 4th wave is free TLP).
// ---------------------------------------------------------------------------
template<int C, int K, int HIN, int WIN, int KWAVES, int NWAVES, int KSETS,
         int NT, typename OutT>
__global__ __launch_bounds__(256, 4) void conv_mfma4(
    const f16* __restrict__ in_cl, const f16* __restrict__ wfrag,
    const float* __restrict__ bias, OutT* __restrict__ out)
{
    constexpr int HOUT = HIN - 2, WOUT = WIN - 2, NPX = HOUT * WOUT;
    constexpr int NC = C / 32;
    constexpr int NKG = K / 32;
    constexpr int PXT = NWAVES * NT * 32;
    constexpr int RM0 = (PXT - 1) / WOUT + 3;
    constexpr int ROWSMAX = RM0 < HIN ? RM0 : HIN;

    __shared__ f16 in_s[ROWSMAX * WIN * 32];

    int tid = threadIdx.x;
    int lane = tid & 63, widx = tid >> 6;
    int ky = widx % KWAVES, ny = widx / KWAVES;
    int n = lane & 31, h = lane >> 5;
    int pt = blockIdx.x, kt = blockIdx.y, b = blockIdx.z;

    int px0 = pt * PXT;
    int row_lo = px0 / WOUT;
    int px_last = (px0 + PXT < NPX ? px0 + PXT : NPX) - 1;
    int rows = px_last / WOUT + 3 - row_lo;
    int tot16 = rows * WIN * 4;

    int pp0[NT], pgg[NT], plin[NT];
    #pragma unroll
    for (int nt = 0; nt < NT; nt++) {
        int p = px0 + (ny * NT + nt) * 32 + n;
        plin[nt] = p;
        int pc = p < NPX ? p : NPX - 1;
        int y = pc / WOUT, x = pc % WOUT;
        pgg[nt] = y * WIN + x;
        pp0[nt] = pgg[nt] - row_lo * WIN;
    }

    floatx16 acc[KSETS][NT];
    #pragma unroll
    for (int ks = 0; ks < KSETS; ks++)
        #pragma unroll
        for (int nt = 0; nt < NT; nt++)
            #pragma unroll
            for (int r = 0; r < 16; r++) acc[ks][nt][r] = 0.f;

    int kgbase = (kt * KWAVES + ky) * KSETS;
    const f16* inb = in_cl + ((size_t)b * (HIN * WIN) + row_lo * WIN) * C;

    for (int c0 = 0; c0 < NC; c0++) {
        for (int e = tid; e < tot16; e += 256) {
            int pp = e >> 2, sg = e & 3;
            uint4 v = *(const uint4*)(inb + (size_t)pp * C + c0 * 32 + sg * 8);
            *(uint4*)(in_s + pp * 32 + sg * 8) = v;
        }
        __syncthreads();
        #pragma unroll
        for (int rs = 0; rs < 9; rs++) {
            int d = (rs / 3) * WIN + (rs % 3);
            #pragma unroll
            for (int kh = 0; kh < 2; kh++) {
                half8 af[KSETS];
                #pragma unroll
                for (int ks = 0; ks < KSETS; ks++)
                    af[ks] = *(const half8*)(wfrag +
                        ((((size_t)c0 * 9 + rs) * NKG + kgbase + ks) * 2 + kh) * 512 +
                        (size_t)lane * 8);
                half8 bf[NT];
                #pragma unroll
                for (int nt = 0; nt < NT; nt++) {
                    int pg = pgg[nt] + d;
                    int slot = (kh * 2 + h) ^ ((pg >> 1) & 3);
                    bf[nt] = *(half8*)(in_s + (pp0[nt] + d) * 32 + slot * 8);
                }
                #pragma unroll
                for (int ks = 0; ks < KSETS; ks++)
                    #pragma unroll
                    for (int nt = 0; nt < NT; nt++)
                        acc[ks][nt] = __builtin_amdgcn_mfma_f32_32x32x16_f16(
                            af[ks], bf[nt], acc[ks][nt], 0, 0, 0);
            }
        }
        __syncthreads();
    }

    #pragma unroll
    for (int ks = 0; ks < KSETS; ks++) {
        #pragma unroll
        for (int r = 0; r < 16; r++) {
            int krow = (r & 3) + 8 * (r >> 2) + 4 * h;
            int k = (kgbase + ks) * 32 + krow;
            float bv = bias[k];
            #pragma unroll
            for (int nt = 0; nt < NT; nt++) {
                if (plin[nt] < NPX) {
                    float v = acc[ks][nt][r] + bv;
                    v = v > 0.f ? v : 0.f;
                    out[((size_t)b * K + k) * NPX + plin[nt]] = (OutT)v;
                }
            }
        }
    }
}

// ---------------------------------------------------------------------------
// maxpool + layout convert (channel-last swizzled f16 for conv3).
// ---------------------------------------------------------------------------
__global__ __launch_bounds__(256) void maxpool_cl(
    const f16* __restrict__ h2, f16* __restrict__ outp)
{
    __shared__ f16 tile[100][34];
    int b = blockIdx.x, kg = blockIdx.y;
    int tid = threadIdx.x;
    for (int e = tid; e < 3200; e += 256) {
        int px = e % 100;
        int kk = e / 100;
        int y = px / 10, x = px % 10;
        const f16* p = h2 + (((size_t)(b * 512 + kg * 32 + kk)) * 20 + 2 * y) * 20 + 2 * x;
        float v = fmaxf(fmaxf((float)p[0], (float)p[1]),
                        fmaxf((float)p[20], (float)p[21]));
        tile[px][kk] = (f16)v;
    }
    __syncthreads();
    for (int e = tid; e < 3200; e += 256) {
        int kk = e & 31, px = e >> 5;
        int slot = (kk >> 3) ^ ((px >> 1) & 3);
        outp[((size_t)b * 100 + px) * 512 + kg * 32 + (slot << 3) + (kk & 7)] = tile[px][kk];
    }
}

// ---------------------------------------------------------------------------
// pc_w transpose: (64,1024,9) -> (1024,9,64)
// ---------------------------------------------------------------------------
__global__ void transpose_pcw_kernel(const float* __restrict__ w, float* __restrict__ wT, int total)
{
    int idx = blockIdx.x * 256 + threadIdx.x;
    if (idx >= total) return;
    int rs = idx % 9;
    int c  = (idx / 9) % 1024;
    int k  = idx / (9 * 1024);
    wT[((size_t)c * 9 + rs) * 64 + k] = w[idx];
}

// ---------------------------------------------------------------------------
// hp_init: hp[b,k,p] = pc_b[k]  (bias pre-fill for split-K pc conv)
// ---------------------------------------------------------------------------
__global__ __launch_bounds__(256) void hp_init(
    float* __restrict__ hp, const float* __restrict__ bias)
{
    int idx = blockIdx.x * 256 + threadIdx.x;
    if (idx >= 128 * 576) return;
    int k = (idx / 9) & 63;
    hp[idx] = bias[k];
}

// ---------------------------------------------------------------------------
// pc conv split-K: grid (b=128, ch=16 chunks of 64 c). Partial sums
// atomicAdd into bias-pre-initialized hp; relu deferred to t_kernel.
// ---------------------------------------------------------------------------
__global__ __launch_bounds__(256) void pc_conv_split(
    const float* __restrict__ h3, const float* __restrict__ wT,
    float* __restrict__ hp)
{
    __shared__ float in_s[64][64];
    __shared__ float red[4][64][9];
    int b = blockIdx.x, c0 = blockIdx.y * 64;
    int tid = threadIdx.x;
    int k = tid & 63, cq = tid >> 6;
    float acc[9];
    #pragma unroll
    for (int p = 0; p < 9; p++) acc[p] = 0.f;
    for (int e = tid; e < 64 * 64; e += 256) {
        int cc = e >> 6, px = e & 63;
        in_s[cc][px] = h3[((size_t)b * 1024 + c0 + cc) * 64 + px];
    }
    __syncthreads();
    for (int ci = 0; ci < 16; ci++) {
        int cc = cq * 16 + ci;
        float wr[9];
        #pragma unroll
        for (int rs = 0; rs < 9; rs++)
            wr[rs] = wT[((size_t)(c0 + cc) * 9 + rs) * 64 + k];
        #pragma unroll
        for (int p = 0; p < 9; p++) {
            int iy = (p / 3) * 2, ix = (p % 3) * 2;
            #pragma unroll
            for (int r = 0; r < 3; r++)
                #pragma unroll
                for (int s = 0; s < 3; s++)
                    acc[p] += in_s[cc][(iy + r) * 8 + ix + s] * wr[r * 3 + s];
        }
    }
    #pragma unroll
    for (int p = 0; p < 9; p++) red[cq][k][p] = acc[p];
    __syncthreads();
    for (int e2 = tid; e2 < 576; e2 += 256) {
        int k2 = e2 / 9, p = e2 % 9;
        float v = red[0][k2][p] + red[1][k2][p] + red[2][k2][p] + red[3][k2][p];
        atomicAdd(&hp[((size_t)b * 64 + k2) * 9 + p], v);
    }
}

// ---------------------------------------------------------------------------
// t_kernel: hp is PRE-ACTIVATION now — relu applied on load.
// ---------------------------------------------------------------------------
__global__ void t_kernel(const float* __restrict__ basis, const float* __restrict__ hp,
                         float* __restrict__ t)
{
    int idx = blockIdx.x * 256 + threadIdx.x;
    if (idx >= 128 * 32 * 8 * 8) return;
    int g = idx & 7, d = (idx >> 3) & 7, c = (idx >> 6) & 31, b = idx >> 11;
    const float* bs = basis + (size_t)((c * 8 + d) * 8) * 9;
    const float* hb = hp + ((size_t)b * 64 + g * 8) * 9;
    float s = 0.f;
    #pragma unroll
    for (int e = 0; e < 8; e++)
        #pragma unroll
        for (int p = 0; p < 9; p++)
            s += bs[e * 9 + p] * fmaxf(hb[e * 9 + p], 0.f);
    t[idx] = s;
}

__global__ void combine_kernel(const float* __restrict__ wb, const float* __restrict__ t,
                               float* __restrict__ feat)
{
    int idx = blockIdx.x * 256 + threadIdx.x;
    if (idx >= 128 * 64) return;
    int o = idx & 63, b = idx >> 6;
    int f = o >> 3, d = o & 7;
    const float* wbb = wb + (size_t)b * 2056;
    const float* tb = t + (size_t)b * 2048;
    float s = wbb[2048 + f];
    for (int c = 0; c < 32; c++)
        #pragma unroll
        for (int g = 0; g < 8; g++)
            s += wbb[(f * 8 + g) * 32 + c] * tb[(c * 8 + d) * 8 + g];
    feat[idx] = s > 0.f ? s : 0.f;
}

__global__ void final_kernel(const float* __restrict__ feat, const float* __restrict__ c2w,
                             const float* __restrict__ c2b, float* __restrict__ out)
{
    int idx = blockIdx.x * 256 + threadIdx.x;
    if (idx >= 128 * 16) return;
    int j = idx & 15, b = idx >> 4;
    float s = c2b[j];
    #pragma unroll
    for (int o = 0; o < 64; o++)
        s += feat[b * 64 + o] * c2w[j * 64 + o];
    out[idx] = s;
}

// ---------------------------------------------------------------------------
extern "C" void kernel_launch(void* const* d_in, const int* in_sizes, int n_in,
                              void* d_out, int out_size, void* d_ws, size_t ws_size,
                              hipStream_t stream)
{
    const float* obs     = (const float*)d_in[0];
    const float* patch   = (const float*)d_in[1];
    const float* enc_w1  = (const float*)d_in[2];
    const float* enc_b1  = (const float*)d_in[3];
    const float* enc_w2  = (const float*)d_in[4];
    const float* enc_b2  = (const float*)d_in[5];
    const float* enc_w3  = (const float*)d_in[6];
    const float* enc_b3  = (const float*)d_in[7];
    const float* pc_w    = (const float*)d_in[8];
    const float* pc_b    = (const float*)d_in[9];
    const float* es_w1   = (const float*)d_in[10];
    const float* es_b1   = (const float*)d_in[11];
    const float* es_w2   = (const float*)d_in[12];
    const float* es_b2   = (const float*)d_in[13];
    const float* ih_w1   = (const float*)d_in[14];
    const float* ih_b1   = (const float*)d_in[15];
    const float* ih_w2   = (const float*)d_in[16];
    const float* ih_b2   = (const float*)d_in[17];
    const float* ih_fc_w = (const float*)d_in[18];
    const float* ih_fc_b = (const float*)d_in[19];
    const float* df_w    = (const float*)d_in[20];
    const float* df_b    = (const float*)d_in[21];
    const float* basis   = (const float*)d_in[22];
    const float* c2_w    = (const float*)d_in[23];
    const float* c2_b    = (const float*)d_in[24];

    float* ws = (float*)d_ws;
    float* es1   = ws;
    float* df_in = ws + 131072;
    float* ih1   = ws + 262144;
    float* ih2   = ws + 1441792;
    f16*   h1h   = (f16*)ws;                    // region A (after FC stack dead)
    f16*   hpool = (f16*)ws;                    // region A (after h1h dead)
    f16*   h2h   = (f16*)(ws + 7929856);        // region B
    float* h3    = ws + 7929856;                // region B (after h2h dead)
    float* wb    = ws + 21037056;
    float* pcwT  = ws + 21300224;
    float* hp    = ws + 21890048;
    float* tbuf  = ws + 21963776;
    float* feat  = ws + 22225920;
    f16*   w2h   = (f16*)(ws + 22234112);
    f16*   w3h   = (f16*)(ws + 22823936);
    float* wT2   = ws + 25183232;

    // --- weight transforms ---
    wtrans_kernel<<<1179648 / 256, 256, 0, stream>>>(enc_w2, w2h, 256, 16, 1179648);
    wtrans_kernel<<<4718592 / 256, 256, 0, stream>>>(enc_w3, w3h, 512, 32, 4718592);
    transpose_pcw_kernel<<<(589824 + 255) / 256, 256, 0, stream>>>(pc_w, pcwT, 589824);
    transpose_w2_kernel<<<(73728 + 255) / 256, 256, 0, stream>>>(ih_w2, wT2);

    // --- FC / in-hand branch (MFMA split-K; pre-activation + relu-on-load) ---
    fc_init<<<(131072 + 255) / 256, 256, 0, stream>>>(es1, es_b1, 128, 1024, 1024);
    fc_mfma<<<dim3(16, 32), 256, 0, stream>>>(obs, es_w1, es1, 1024, 16384, 512, 1024, 0);

    fc_init<<<(65536 + 255) / 256, 256, 0, stream>>>(df_in, es_b2, 128, 512, 1024);
    fc_init<<<(65536 + 255) / 256, 256, 0, stream>>>(df_in + 512, ih_fc_b, 128, 512, 1024);
    fc_mfma<<<dim3(8, 8), 256, 0, stream>>>(es1, es_w2, df_in, 512, 1024, 128, 1024, 1);

    conv_direct_kernel<<<(1179648 + 255) / 256, 256, 0, stream>>>(
        patch + 576, 1152, ih_w1, ih_b1, ih1, 1, 24, 24, 64, 12, 12, 2, 1, 1179648);
    ih2_kernel<<<128, 256, 0, stream>>>(ih1, wT2, ih_b2, ih2);
    fc_mfma<<<dim3(8, 16), 256, 0, stream>>>(ih2, ih_fc_w, df_in + 512, 512, 4608, 288, 1024, 0);

    fc_init<<<(263168 + 255) / 256, 256, 0, stream>>>(wb, df_b, 128, 2056, 2056);
    fc_mfma<<<dim3(33, 8), 256, 0, stream>>>(df_in, df_w, wb, 2056, 1024, 128, 2056, 1);

    // --- encoder branch ---
    enc1_kernel<<<15859712 / 256, 256, 0, stream>>>(patch, enc_w1, enc_b1, h1h, 15859712);
    conv_mfma4<256, 512, 22, 22, 2, 2, 2, 2, f16>
        <<<dim3(4, 4, 128), 256, 0, stream>>>(h1h, w2h, enc_b2, h2h);
    maxpool_cl<<<dim3(128, 16), 256, 0, stream>>>(h2h, hpool);
    conv_mfma4<512, 1024, 10, 10, 4, 1, 2, 2, float>
        <<<dim3(1, 4, 128), 256, 0, stream>>>(hpool, w3h, enc_b3, h3);

    // --- pc conv (split-K over 16 channel chunks) ---
    hp_init<<<(73728 + 255) / 256, 256, 0, stream>>>(hp, pc_b);
    pc_conv_split<<<dim3(128, 16), 256, 0, stream>>>(h3, pcwT, hp);

    // --- dynamic-filter epilogue ---
    t_kernel<<<(262144 + 255) / 256, 256, 0, stream>>>(basis, hp, tbuf);
    combine_kernel<<<(8192 + 255) / 256, 256, 0, stream>>>(wb, tbuf, feat);
    final_kernel<<<(2048 + 255) / 256, 256, 0, stream>>>(feat, c2_w, c2_b, (float*)d_out);
}

// Round 11
// 776.349 us; speedup vs baseline: 1.1936x; 1.1936x over previous
//
#include <hip/hip_runtime.h>
#include <cstddef>

#define BATCH 128

typedef _Float16 f16;
typedef _Float16 half8 __attribute__((ext_vector_type(8)));
typedef float floatx16 __attribute__((ext_vector_type(16)));

// ---------------------------------------------------------------------------
// fc_init: out[m, n] = bias[n]
// ---------------------------------------------------------------------------
__global__ __launch_bounds__(256) void fc_init(
    float* __restrict__ out, const float* __restrict__ bias, int M, int N, int stride)
{
    int idx = blockIdx.x * 256 + threadIdx.x;
    if (idx >= M * N) return;
    int n = idx % N, m = idx / N;
    out[(size_t)m * stride + n] = bias[n];
}

// ---------------------------------------------------------------------------
// fc_mfma: split-K FC partial via v_mfma_f32_32x32x16_f16.
// ---------------------------------------------------------------------------
__global__ __launch_bounds__(256) void fc_mfma(
    const float* __restrict__ A, const float* __restrict__ W,
    float* __restrict__ out, int N, int K, int KC, int out_stride, int relu_in)
{
    __shared__ f16 As[128 * 34];
    __shared__ f16 Ws[64 * 34];
    int tid = threadIdx.x;
    int lane = tid & 63, wv = tid >> 6;
    int m32 = lane & 31, h = lane >> 5;
    int n0 = blockIdx.x * 64;
    int k0 = blockIdx.y * KC;

    floatx16 acc[2];
    #pragma unroll
    for (int nt = 0; nt < 2; nt++)
        #pragma unroll
        for (int r = 0; r < 16; r++) acc[nt][r] = 0.f;

    for (int ks = 0; ks < KC; ks += 32) {
        #pragma unroll
        for (int q4 = 0; q4 < 4; q4++) {
            int e = tid + q4 * 256;
            int m = e >> 3, q = e & 7;
            float4 v = *(const float4*)(A + (size_t)m * K + k0 + ks + q * 4);
            if (relu_in) {
                v.x = fmaxf(v.x, 0.f); v.y = fmaxf(v.y, 0.f);
                v.z = fmaxf(v.z, 0.f); v.w = fmaxf(v.w, 0.f);
            }
            f16* dst = As + m * 34 + q * 4;
            dst[0] = (f16)v.x; dst[1] = (f16)v.y; dst[2] = (f16)v.z; dst[3] = (f16)v.w;
        }
        #pragma unroll
        for (int q4 = 0; q4 < 2; q4++) {
            int e = tid + q4 * 256;
            int nn = e >> 3, q = e & 7;
            int n = n0 + nn;
            float4 v = (n < N) ? *(const float4*)(W + (size_t)n * K + k0 + ks + q * 4)
                               : make_float4(0.f, 0.f, 0.f, 0.f);
            f16* dst = Ws + nn * 34 + q * 4;
            dst[0] = (f16)v.x; dst[1] = (f16)v.y; dst[2] = (f16)v.z; dst[3] = (f16)v.w;
        }
        __syncthreads();
        #pragma unroll
        for (int kh = 0; kh < 2; kh++) {
            half8 af = *(const half8*)(As + (wv * 32 + m32) * 34 + kh * 16 + h * 8);
            #pragma unroll
            for (int nt = 0; nt < 2; nt++) {
                half8 bf = *(const half8*)(Ws + (nt * 32 + m32) * 34 + kh * 16 + h * 8);
                acc[nt] = __builtin_amdgcn_mfma_f32_32x32x16_f16(af, bf, acc[nt], 0, 0, 0);
            }
        }
        __syncthreads();
    }
    #pragma unroll
    for (int nt = 0; nt < 2; nt++) {
        #pragma unroll
        for (int r = 0; r < 16; r++) {
            int m = wv * 32 + (r & 3) + 8 * (r >> 2) + 4 * h;
            int n = n0 + nt * 32 + m32;
            if (n < N) atomicAdd(&out[(size_t)m * out_stride + n], acc[nt][r]);
        }
    }
}

// ---------------------------------------------------------------------------
// Direct conv 3x3 (+relu), fp32 — used only for ih1 (C=1).
// ---------------------------------------------------------------------------
__global__ void conv_direct_kernel(
    const float* __restrict__ in, long inBatchStride,
    const float* __restrict__ w, const float* __restrict__ bias,
    float* __restrict__ out,
    int C, int H, int Wd, int K, int OH, int OW, int stride, int pad, int total)
{
    int idx = blockIdx.x * 256 + threadIdx.x;
    if (idx >= total) return;
    int ox = idx % OW;
    int oy = (idx / OW) % OH;
    int k  = (idx / (OW * OH)) % K;
    int b  = idx / (OW * OH * K);
    const float* inb = in + (size_t)b * inBatchStride;
    float s = bias[k];
    for (int c = 0; c < C; c++) {
        const float* ip = inb + (size_t)c * H * Wd;
        const float* wp = w + ((size_t)k * C + c) * 9;
        #pragma unroll
        for (int r = 0; r < 3; r++) {
            int iy = oy * stride - pad + r;
            if (iy < 0 || iy >= H) continue;
            #pragma unroll
            for (int s2 = 0; s2 < 3; s2++) {
                int ix = ox * stride - pad + s2;
                if (ix < 0 || ix >= Wd) continue;
                s += ip[iy * Wd + ix] * wp[r * 3 + s2];
            }
        }
    }
    out[idx] = s > 0.f ? s : 0.f;
}

// ---------------------------------------------------------------------------
// ih_w2 transpose: (128,64,9) -> wT2[(c*9+rs)*128 + k]
// ---------------------------------------------------------------------------
__global__ void transpose_w2_kernel(const float* __restrict__ w, float* __restrict__ wT)
{
    int idx = blockIdx.x * 256 + threadIdx.x;
    if (idx >= 73728) return;
    int k = idx / 576;
    int rem = idx % 576;
    wT[rem * 128 + k] = w[idx];
}

// ---------------------------------------------------------------------------
// ih2: conv 64->128, 12x12 -> 6x6, s2 p1, relu.
// ---------------------------------------------------------------------------
__global__ __launch_bounds__(256) void ih2_kernel(
    const float* __restrict__ ih1, const float* __restrict__ wT2,
    const float* __restrict__ bias, float* __restrict__ out)
{
    __shared__ float in_s[4 * 144];
    __shared__ float w_s[4 * 1152];
    int b = blockIdx.x;
    int tid = threadIdx.x;
    int k = tid & 127, half = tid >> 7;
    int oy0 = half * 3;
    float acc[3][6];
    #pragma unroll
    for (int r = 0; r < 3; r++)
        #pragma unroll
        for (int c = 0; c < 6; c++) acc[r][c] = 0.f;

    for (int c0 = 0; c0 < 64; c0 += 4) {
        for (int e = tid; e < 576; e += 256)
            in_s[e] = ih1[((size_t)b * 64 + c0) * 144 + e];
        for (int e = tid; e < 4608; e += 256)
            w_s[e] = wT2[c0 * 1152 + e];
        __syncthreads();
        #pragma unroll
        for (int cc = 0; cc < 4; cc++) {
            float wr[9];
            #pragma unroll
            for (int rs = 0; rs < 9; rs++) wr[rs] = w_s[cc * 1152 + rs * 128 + k];
            #pragma unroll
            for (int row = 0; row < 3; row++) {
                int oy = oy0 + row;
                #pragma unroll
                for (int r = 0; r < 3; r++) {
                    int iy = 2 * oy - 1 + r;
                    float v[13];
                    if (iy >= 0) {
                        float4 a = *(const float4*)&in_s[cc * 144 + iy * 12];
                        float4 bq = *(const float4*)&in_s[cc * 144 + iy * 12 + 4];
                        float4 cq = *(const float4*)&in_s[cc * 144 + iy * 12 + 8];
                        v[0] = 0.f;
                        v[1] = a.x;  v[2] = a.y;  v[3] = a.z;  v[4] = a.w;
                        v[5] = bq.x; v[6] = bq.y; v[7] = bq.z; v[8] = bq.w;
                        v[9] = cq.x; v[10] = cq.y; v[11] = cq.z; v[12] = cq.w;
                    } else {
                        #pragma unroll
                        for (int u = 0; u < 13; u++) v[u] = 0.f;
                    }
                    #pragma unroll
                    for (int s = 0; s < 3; s++) {
                        float wv = wr[r * 3 + s];
                        #pragma unroll
                        for (int ox = 0; ox < 6; ox++)
                            acc[row][ox] += v[2 * ox + s] * wv;
                    }
                }
            }
        }
        __syncthreads();
    }
    float bv = bias[k];
    #pragma unroll
    for (int row = 0; row < 3; row++)
        #pragma unroll
        for (int ox = 0; ox < 6; ox++) {
            float vv = acc[row][ox] + bv;
            out[((size_t)(b * 128 + k) * 6 + oy0 + row) * 6 + ox] = vv > 0.f ? vv : 0.f;
        }
}

// ---------------------------------------------------------------------------
// enc1: conv 1->256, 24x24 -> 22x22, relu. f16 channel-last, swizzled.
// ---------------------------------------------------------------------------
__global__ void enc1_kernel(const float* __restrict__ patch,
                            const float* __restrict__ w,
                            const float* __restrict__ bias,
                            f16* __restrict__ h1, int total)
{
    int idx = blockIdx.x * 256 + threadIdx.x;
    if (idx >= total) return;
    int k  = idx & 255;
    int pg = (idx >> 8) % 484;
    int b  = idx / (484 * 256);
    int y = pg / 22, x = pg % 22;
    const float* pb = patch + (size_t)b * 1152 + y * 24 + x;
    const float* wk = w + k * 9;
    float s = bias[k];
    #pragma unroll
    for (int r = 0; r < 3; r++)
        #pragma unroll
        for (int c = 0; c < 3; c++)
            s += pb[r * 24 + c] * wk[r * 3 + c];
    s = s > 0.f ? s : 0.f;
    int cpos = (k & ~31) + (((((k >> 3) & 3) ^ ((pg >> 1) & 3))) << 3) + (k & 7);
    h1[((size_t)b * 484 + pg) * 256 + cpos] = (f16)s;
}

// ---------------------------------------------------------------------------
// Weight transform to MFMA-A fragment-major f16.
// ---------------------------------------------------------------------------
__global__ void wtrans_kernel(const float* __restrict__ w, f16* __restrict__ wf,
                              int C, int NKG, int total)
{
    int idx = blockIdx.x * 256 + threadIdx.x;
    if (idx >= total) return;
    int j    = idx & 7;
    int lane = (idx >> 3) & 63;
    int kh   = (idx >> 9) & 1;
    int kg   = (idx >> 10) % NKG;
    int rest = idx / (NKG << 10);
    int rs   = rest % 9;
    int c0   = rest / 9;
    int k = kg * 32 + (lane & 31);
    int c = c0 * 32 + kh * 16 + ((lane >> 5) << 3) + j;
    wf[idx] = (f16)w[((size_t)k * C + c) * 9 + rs];
}

// ---------------------------------------------------------------------------
// conv_mfma4: 3x3 conv s1 p0 +relu, v_mfma_f32_32x32x16_f16.
// acc[2][2] = 64 AGPR + 64 arch VGPR. __launch_bounds__(256,3):
// 3 blocks/CU is the measured sweet spot — R10 showed 4 blocks/CU
// saturates the LDS pipe (MfmaUtil 36->27, dur 183->235). Do not raise.
// ---------------------------------------------------------------------------
template<int C, int K, int HIN, int WIN, int KWAVES, int NWAVES, int KSETS,
         int NT, typename OutT>
__global__ __launch_bounds__(256, 3) void conv_mfma4(
    const f16* __restrict__ in_cl, const f16* __restrict__ wfrag,
    const float* __restrict__ bias, OutT* __restrict__ out)
{
    constexpr int HOUT = HIN - 2, WOUT = WIN - 2, NPX = HOUT * WOUT;
    constexpr int NC = C / 32;
    constexpr int NKG = K / 32;
    constexpr int PXT = NWAVES * NT * 32;
    constexpr int RM0 = (PXT - 1) / WOUT + 3;
    constexpr int ROWSMAX = RM0 < HIN ? RM0 : HIN;

    __shared__ f16 in_s[ROWSMAX * WIN * 32];

    int tid = threadIdx.x;
    int lane = tid & 63, widx = tid >> 6;
    int ky = widx % KWAVES, ny = widx / KWAVES;
    int n = lane & 31, h = lane >> 5;
    int pt = blockIdx.x, kt = blockIdx.y, b = blockIdx.z;

    int px0 = pt * PXT;
    int row_lo = px0 / WOUT;
    int px_last = (px0 + PXT < NPX ? px0 + PXT : NPX) - 1;
    int rows = px_last / WOUT + 3 - row_lo;
    int tot16 = rows * WIN * 4;

    int pp0[NT], pgg[NT], plin[NT];
    #pragma unroll
    for (int nt = 0; nt < NT; nt++) {
        int p = px0 + (ny * NT + nt) * 32 + n;
        plin[nt] = p;
        int pc = p < NPX ? p : NPX - 1;
        int y = pc / WOUT, x = pc % WOUT;
        pgg[nt] = y * WIN + x;
        pp0[nt] = pgg[nt] - row_lo * WIN;
    }

    floatx16 acc[KSETS][NT];
    #pragma unroll
    for (int ks = 0; ks < KSETS; ks++)
        #pragma unroll
        for (int nt = 0; nt < NT; nt++)
            #pragma unroll
            for (int r = 0; r < 16; r++) acc[ks][nt][r] = 0.f;

    int kgbase = (kt * KWAVES + ky) * KSETS;
    const f16* inb = in_cl + ((size_t)b * (HIN * WIN) + row_lo * WIN) * C;

    for (int c0 = 0; c0 < NC; c0++) {
        for (int e = tid; e < tot16; e += 256) {
            int pp = e >> 2, sg = e & 3;
            uint4 v = *(const uint4*)(inb + (size_t)pp * C + c0 * 32 + sg * 8);
            *(uint4*)(in_s + pp * 32 + sg * 8) = v;
        }
        __syncthreads();
        #pragma unroll
        for (int rs = 0; rs < 9; rs++) {
            int d = (rs / 3) * WIN + (rs % 3);
            #pragma unroll
            for (int kh = 0; kh < 2; kh++) {
                half8 af[KSETS];
                #pragma unroll
                for (int ks = 0; ks < KSETS; ks++)
                    af[ks] = *(const half8*)(wfrag +
                        ((((size_t)c0 * 9 + rs) * NKG + kgbase + ks) * 2 + kh) * 512 +
                        (size_t)lane * 8);
                half8 bf[NT];
                #pragma unroll
                for (int nt = 0; nt < NT; nt++) {
                    int pg = pgg[nt] + d;
                    int slot = (kh * 2 + h) ^ ((pg >> 1) & 3);
                    bf[nt] = *(half8*)(in_s + (pp0[nt] + d) * 32 + slot * 8);
                }
                #pragma unroll
                for (int ks = 0; ks < KSETS; ks++)
                    #pragma unroll
                    for (int nt = 0; nt < NT; nt++)
                        acc[ks][nt] = __builtin_amdgcn_mfma_f32_32x32x16_f16(
                            af[ks], bf[nt], acc[ks][nt], 0, 0, 0);
            }
        }
        __syncthreads();
    }

    #pragma unroll
    for (int ks = 0; ks < KSETS; ks++) {
        #pragma unroll
        for (int r = 0; r < 16; r++) {
            int krow = (r & 3) + 8 * (r >> 2) + 4 * h;
            int k = (kgbase + ks) * 32 + krow;
            float bv = bias[k];
            #pragma unroll
            for (int nt = 0; nt < NT; nt++) {
                if (plin[nt] < NPX) {
                    float v = acc[ks][nt][r] + bv;
                    v = v > 0.f ? v : 0.f;
                    out[((size_t)b * K + k) * NPX + plin[nt]] = (OutT)v;
                }
            }
        }
    }
}

// ---------------------------------------------------------------------------
// maxpool + layout convert (channel-last swizzled f16 for conv3).
// ---------------------------------------------------------------------------
__global__ __launch_bounds__(256) void maxpool_cl(
    const f16* __restrict__ h2, f16* __restrict__ outp)
{
    __shared__ f16 tile[100][34];
    int b = blockIdx.x, kg = blockIdx.y;
    int tid = threadIdx.x;
    for (int e = tid; e < 3200; e += 256) {
        int px = e % 100;
        int kk = e / 100;
        int y = px / 10, x = px % 10;
        const f16* p = h2 + (((size_t)(b * 512 + kg * 32 + kk)) * 20 + 2 * y) * 20 + 2 * x;
        float v = fmaxf(fmaxf((float)p[0], (float)p[1]),
                        fmaxf((float)p[20], (float)p[21]));
        tile[px][kk] = (f16)v;
    }
    __syncthreads();
    for (int e = tid; e < 3200; e += 256) {
        int kk = e & 31, px = e >> 5;
        int slot = (kk >> 3) ^ ((px >> 1) & 3);
        outp[((size_t)b * 100 + px) * 512 + kg * 32 + (slot << 3) + (kk & 7)] = tile[px][kk];
    }
}

// ---------------------------------------------------------------------------
// pc_w transpose: (64,1024,9) -> (1024,9,64)
// ---------------------------------------------------------------------------
__global__ void transpose_pcw_kernel(const float* __restrict__ w, float* __restrict__ wT, int total)
{
    int idx = blockIdx.x * 256 + threadIdx.x;
    if (idx >= total) return;
    int rs = idx % 9;
    int c  = (idx / 9) % 1024;
    int k  = idx / (9 * 1024);
    wT[((size_t)c * 9 + rs) * 64 + k] = w[idx];
}

// ---------------------------------------------------------------------------
// hp_init: hp[b,k,p] = pc_b[k]
// ---------------------------------------------------------------------------
__global__ __launch_bounds__(256) void hp_init(
    float* __restrict__ hp, const float* __restrict__ bias)
{
    int idx = blockIdx.x * 256 + threadIdx.x;
    if (idx >= 128 * 576) return;
    int k = (idx / 9) & 63;
    hp[idx] = bias[k];
}

// ---------------------------------------------------------------------------
// pc conv split-K: grid (b=128, ch=16 chunks of 64 c).
// ---------------------------------------------------------------------------
__global__ __launch_bounds__(256) void pc_conv_split(
    const float* __restrict__ h3, const float* __restrict__ wT,
    float* __restrict__ hp)
{
    __shared__ float in_s[64][64];
    __shared__ float red[4][64][9];
    int b = blockIdx.x, c0 = blockIdx.y * 64;
    int tid = threadIdx.x;
    int k = tid & 63, cq = tid >> 6;
    float acc[9];
    #pragma unroll
    for (int p = 0; p < 9; p++) acc[p] = 0.f;
    for (int e = tid; e < 64 * 64; e += 256) {
        int cc = e >> 6, px = e & 63;
        in_s[cc][px] = h3[((size_t)b * 1024 + c0 + cc) * 64 + px];
    }
    __syncthreads();
    for (int ci = 0; ci < 16; ci++) {
        int cc = cq * 16 + ci;
        float wr[9];
        #pragma unroll
        for (int rs = 0; rs < 9; rs++)
            wr[rs] = wT[((size_t)(c0 + cc) * 9 + rs) * 64 + k];
        #pragma unroll
        for (int p = 0; p < 9; p++) {
            int iy = (p / 3) * 2, ix = (p % 3) * 2;
            #pragma unroll
            for (int r = 0; r < 3; r++)
                #pragma unroll
                for (int s = 0; s < 3; s++)
                    acc[p] += in_s[cc][(iy + r) * 8 + ix + s] * wr[r * 3 + s];
        }
    }
    #pragma unroll
    for (int p = 0; p < 9; p++) red[cq][k][p] = acc[p];
    __syncthreads();
    for (int e2 = tid; e2 < 576; e2 += 256) {
        int k2 = e2 / 9, p = e2 % 9;
        float v = red[0][k2][p] + red[1][k2][p] + red[2][k2][p] + red[3][k2][p];
        atomicAdd(&hp[((size_t)b * 64 + k2) * 9 + p], v);
    }
}

// ---------------------------------------------------------------------------
// t_kernel: hp is PRE-ACTIVATION — relu applied on load.
// ---------------------------------------------------------------------------
__global__ void t_kernel(const float* __restrict__ basis, const float* __restrict__ hp,
                         float* __restrict__ t)
{
    int idx = blockIdx.x * 256 + threadIdx.x;
    if (idx >= 128 * 32 * 8 * 8) return;
    int g = idx & 7, d = (idx >> 3) & 7, c = (idx >> 6) & 31, b = idx >> 11;
    const float* bs = basis + (size_t)((c * 8 + d) * 8) * 9;
    const float* hb = hp + ((size_t)b * 64 + g * 8) * 9;
    float s = 0.f;
    #pragma unroll
    for (int e = 0; e < 8; e++)
        #pragma unroll
        for (int p = 0; p < 9; p++)
            s += bs[e * 9 + p] * fmaxf(hb[e * 9 + p], 0.f);
    t[idx] = s;
}

__global__ void combine_kernel(const float* __restrict__ wb, const float* __restrict__ t,
                               float* __restrict__ feat)
{
    int idx = blockIdx.x * 256 + threadIdx.x;
    if (idx >= 128 * 64) return;
    int o = idx & 63, b = idx >> 6;
    int f = o >> 3, d = o & 7;
    const float* wbb = wb + (size_t)b * 2056;
    const float* tb = t + (size_t)b * 2048;
    float s = wbb[2048 + f];
    for (int c = 0; c < 32; c++)
        #pragma unroll
        for (int g = 0; g < 8; g++)
            s += wbb[(f * 8 + g) * 32 + c] * tb[(c * 8 + d) * 8 + g];
    feat[idx] = s > 0.f ? s : 0.f;
}

__global__ void final_kernel(const float* __restrict__ feat, const float* __restrict__ c2w,
                             const float* __restrict__ c2b, float* __restrict__ out)
{
    int idx = blockIdx.x * 256 + threadIdx.x;
    if (idx >= 128 * 16) return;
    int j = idx & 15, b = idx >> 4;
    float s = c2b[j];
    #pragma unroll
    for (int o = 0; o < 64; o++)
        s += feat[b * 64 + o] * c2w[j * 64 + o];
    out[idx] = s;
}

// ---------------------------------------------------------------------------
extern "C" void kernel_launch(void* const* d_in, const int* in_sizes, int n_in,
                              void* d_out, int out_size, void* d_ws, size_t ws_size,
                              hipStream_t stream)
{
    const float* obs     = (const float*)d_in[0];
    const float* patch   = (const float*)d_in[1];
    const float* enc_w1  = (const float*)d_in[2];
    const float* enc_b1  = (const float*)d_in[3];
    const float* enc_w2  = (const float*)d_in[4];
    const float* enc_b2  = (const float*)d_in[5];
    const float* enc_w3  = (const float*)d_in[6];
    const float* enc_b3  = (const float*)d_in[7];
    const float* pc_w    = (const float*)d_in[8];
    const float* pc_b    = (const float*)d_in[9];
    const float* es_w1   = (const float*)d_in[10];
    const float* es_b1   = (const float*)d_in[11];
    const float* es_w2   = (const float*)d_in[12];
    const float* es_b2   = (const float*)d_in[13];
    const float* ih_w1   = (const float*)d_in[14];
    const float* ih_b1   = (const float*)d_in[15];
    const float* ih_w2   = (const float*)d_in[16];
    const float* ih_b2   = (const float*)d_in[17];
    const float* ih_fc_w = (const float*)d_in[18];
    const float* ih_fc_b = (const float*)d_in[19];
    const float* df_w    = (const float*)d_in[20];
    const float* df_b    = (const float*)d_in[21];
    const float* basis   = (const float*)d_in[22];
    const float* c2_w    = (const float*)d_in[23];
    const float* c2_b    = (const float*)d_in[24];

    float* ws = (float*)d_ws;
    float* es1   = ws;
    float* df_in = ws + 131072;
    float* ih1   = ws + 262144;
    float* ih2   = ws + 1441792;
    f16*   h1h   = (f16*)ws;                    // region A (after FC stack dead)
    f16*   hpool = (f16*)ws;                    // region A (after h1h dead)
    f16*   h2h   = (f16*)(ws + 7929856);        // region B
    float* h3    = ws + 7929856;                // region B (after h2h dead)
    float* wb    = ws + 21037056;
    float* pcwT  = ws + 21300224;
    float* hp    = ws + 21890048;
    float* tbuf  = ws + 21963776;
    float* feat  = ws + 22225920;
    f16*   w2h   = (f16*)(ws + 22234112);
    f16*   w3h   = (f16*)(ws + 22823936);
    float* wT2   = ws + 25183232;

    // --- weight transforms ---
    wtrans_kernel<<<1179648 / 256, 256, 0, stream>>>(enc_w2, w2h, 256, 16, 1179648);
    wtrans_kernel<<<4718592 / 256, 256, 0, stream>>>(enc_w3, w3h, 512, 32, 4718592);
    transpose_pcw_kernel<<<(589824 + 255) / 256, 256, 0, stream>>>(pc_w, pcwT, 589824);
    transpose_w2_kernel<<<(73728 + 255) / 256, 256, 0, stream>>>(ih_w2, wT2);

    // --- FC / in-hand branch (MFMA split-K; pre-activation + relu-on-load) ---
    fc_init<<<(131072 + 255) / 256, 256, 0, stream>>>(es1, es_b1, 128, 1024, 1024);
    fc_mfma<<<dim3(16, 32), 256, 0, stream>>>(obs, es_w1, es1, 1024, 16384, 512, 1024, 0);

    fc_init<<<(65536 + 255) / 256, 256, 0, stream>>>(df_in, es_b2, 128, 512, 1024);
    fc_init<<<(65536 + 255) / 256, 256, 0, stream>>>(df_in + 512, ih_fc_b, 128, 512, 1024);
    fc_mfma<<<dim3(8, 8), 256, 0, stream>>>(es1, es_w2, df_in, 512, 1024, 128, 1024, 1);

    conv_direct_kernel<<<(1179648 + 255) / 256, 256, 0, stream>>>(
        patch + 576, 1152, ih_w1, ih_b1, ih1, 1, 24, 24, 64, 12, 12, 2, 1, 1179648);
    ih2_kernel<<<128, 256, 0, stream>>>(ih1, wT2, ih_b2, ih2);
    fc_mfma<<<dim3(8, 16), 256, 0, stream>>>(ih2, ih_fc_w, df_in + 512, 512, 4608, 288, 1024, 0);

    fc_init<<<(263168 + 255) / 256, 256, 0, stream>>>(wb, df_b, 128, 2056, 2056);
    fc_mfma<<<dim3(33, 8), 256, 0, stream>>>(df_in, df_w, wb, 2056, 1024, 128, 2056, 1);

    // --- encoder branch ---
    enc1_kernel<<<15859712 / 256, 256, 0, stream>>>(patch, enc_w1, enc_b1, h1h, 15859712);
    conv_mfma4<256, 512, 22, 22, 2, 2, 2, 2, f16>
        <<<dim3(4, 4, 128), 256, 0, stream>>>(h1h, w2h, enc_b2, h2h);
    maxpool_cl<<<dim3(128, 16), 256, 0, stream>>>(h2h, hpool);
    conv_mfma4<512, 1024, 10, 10, 4, 1, 2, 2, float>
        <<<dim3(1, 4, 128), 256, 0, stream>>>(hpool, w3h, enc_b3, h3);

    // --- pc conv (split-K over 16 channel chunks) ---
    hp_init<<<(73728 + 255) / 256, 256, 0, stream>>>(hp, pc_b);
    pc_conv_split<<<dim3(128, 16), 256, 0, stream>>>(h3, pcwT, hp);

    // --- dynamic-filter epilogue ---
    t_kernel<<<(262144 + 255) / 256, 256, 0, stream>>>(basis, hp, tbuf);
    combine_kernel<<<(8192 + 255) / 256, 256, 0, stream>>>(wb, tbuf, feat);
    final_kernel<<<(2048 + 255) / 256, 256, 0, stream>>>(feat, c2_w, c2_b, (float*)d_out);
}